// Round 1
// baseline (199.068 us; speedup 1.0000x reference)
//
#include <hip/hip_runtime.h>
#include <math.h>

#define TWO_PI_F 6.28318530717958647692f
#define PI_F     3.14159265358979323846f

// ---------------- CE kernel: one wave (64 lanes) per row --------------------
__global__ __launch_bounds__(256) void ce_kernel(const float* __restrict__ outputs,
                                                 const int* __restrict__ targets,
                                                 int B, int C,
                                                 float* __restrict__ acc) {
    const int wave = threadIdx.x >> 6;
    const int lane = threadIdx.x & 63;
    const int row  = blockIdx.x * 4 + wave;

    float contrib = 0.0f;
    if (row < B) {
        const float* rowp = outputs + (size_t)row * (size_t)C;
        float v[16];
        int cnt = 0;
        float m = -INFINITY;
        for (int j = lane; j < C; j += 64) {
            float x = rowp[j];
            v[cnt++] = x;
            m = fmaxf(m, x);
        }
        // wave-wide max
        for (int off = 32; off; off >>= 1)
            m = fmaxf(m, __shfl_xor(m, off, 64));
        float s = 0.0f;
        for (int i = 0; i < cnt; i++)
            s += expf(v[i] - m);
        // wave-wide sum
        for (int off = 32; off; off >>= 1)
            s += __shfl_xor(s, off, 64);
        if (lane == 0) {
            int t = targets[row];
            float tv = rowp[t];               // L1/L2 hit (row just read)
            contrib = m + logf(s) - tv;       // -log_softmax[target]
        }
    }

    __shared__ float part[4];
    if (lane == 0) part[wave] = contrib;
    __syncthreads();
    if (threadIdx.x == 0)
        atomicAdd(acc, part[0] + part[1] + part[2] + part[3]);
}

// ---------------- resonance kernel: one thread per edge ---------------------
__global__ __launch_bounds__(256) void res_kernel(const float* __restrict__ phase,
                                                  const int* __restrict__ esrc,
                                                  const int* __restrict__ edst,
                                                  int N, int E,
                                                  float* __restrict__ acc) {
    const int i = blockIdx.x * blockDim.x + threadIdx.x;
    float d = 0.0f;
    if (i < E) {
        int s = esrc[i];
        int t = edst[i];
        float a = phase[(size_t)s * (size_t)N + (size_t)t];
        float b = phase[(size_t)t * (size_t)N + (size_t)s];
        d = fabsf(a - b);
        d = fmodf(d, TWO_PI_F);
        if (d > PI_F) d = TWO_PI_F - d;
    }
    for (int off = 32; off; off >>= 1)
        d += __shfl_xor(d, off, 64);

    __shared__ float part[4];
    const int lane = threadIdx.x & 63, wave = threadIdx.x >> 6;
    if (lane == 0) part[wave] = d;
    __syncthreads();
    if (threadIdx.x == 0)
        atomicAdd(acc + 1, part[0] + part[1] + part[2] + part[3]);
}

// ---------------- finalize --------------------------------------------------
__global__ void fin_kernel(const float* __restrict__ acc,
                           float* __restrict__ out,
                           float invB, float invE) {
    out[0] = acc[0] * invB + 0.1f * (acc[1] * invE);
}

extern "C" void kernel_launch(void* const* d_in, const int* in_sizes, int n_in,
                              void* d_out, int out_size, void* d_ws, size_t ws_size,
                              hipStream_t stream) {
    const float* outputs = (const float*)d_in[0];
    const int*   targets = (const int*)d_in[1];
    const float* phase   = (const float*)d_in[2];
    const int*   esrc    = (const int*)d_in[3];
    const int*   edst    = (const int*)d_in[4];

    const int B = in_sizes[1];
    const int C = in_sizes[0] / B;
    const int E = in_sizes[3];
    // N from N*N element count
    int N = 1;
    while ((long long)N * (long long)N < (long long)in_sizes[2]) N++;

    float* acc = (float*)d_ws;              // acc[0] = CE sum, acc[1] = resonance sum
    hipMemsetAsync(acc, 0, 2 * sizeof(float), stream);

    // CE: one wave per row, 4 waves per block
    const int ce_blocks = (B + 3) / 4;
    ce_kernel<<<ce_blocks, 256, 0, stream>>>(outputs, targets, B, C, acc);

    // resonance: one thread per edge
    const int res_blocks = (E + 255) / 256;
    res_kernel<<<res_blocks, 256, 0, stream>>>(phase, esrc, edst, N, E, acc);

    fin_kernel<<<1, 1, 0, stream>>>(acc, (float*)d_out, 1.0f / (float)B, 1.0f / (float)E);
}